// Round 3
// baseline (100.760 us; speedup 1.0000x reference)
//
#include <hip/hip_runtime.h>
#include <math.h>

typedef unsigned int uint32;
typedef __bf16 bf16x8 __attribute__((ext_vector_type(8)));
typedef float f32x16 __attribute__((ext_vector_type(16)));

#define BROWS 8192
#define WDIM 256
#define NT 3             // 128x128 tile pairs: t0=(0,0), t1=(0,1), t2=(1,1)
#define CHUNKS 64        // 64 * 128 rows = 8192
#define TILE_ELEMS 16384
#define GRID_BLKS (NT * CHUNKS)   // 192 blocks; 64KB LDS -> all co-resident on 256 CUs

// ws float layout (all ATOMIC-accessed, zeroed in-kernel each launch):
// [0 .. 49151]       G tiles f32: t*16384 + row*128 + col   (3 x 128x128)
// [49152 .. 49407]   colsum f32 [256]
#define WS_G 0
#define WS_CS (NT * TILE_ELEMS)
#define WS_NATOM (WS_CS + WDIM)          // 49408 floats
#define ZSLICE 258                       // ceil(49408/192)

// Monotonic generation counters (device globals: ws is re-poisoned every
// iteration). Each grows by exactly GRID_BLKS per launch -> target is the
// next multiple of GRID_BLKS; graph replays need no reset.
__device__ unsigned g_zeroed = 0;
__device__ unsigned g_done = 0;

__device__ __forceinline__ uint32 pack2bf(float lo, float hi) {
    uint32 a = __float_as_uint(lo), b = __float_as_uint(hi);
    a = (a + 0x7FFFu + ((a >> 16) & 1u)) >> 16;   // RNE fp32->bf16
    b = (b + 0x7FFFu + ((b >> 16) & 1u)) >> 16;
    return (a & 0xFFFFu) | (b << 16);
}
__device__ __forceinline__ float bflo(uint32 v) { return __uint_as_float(v << 16); }
__device__ __forceinline__ float bfhi(uint32 v) { return __uint_as_float(v & 0xFFFF0000u); }

// LDS layout: U[col][krp] (krp = k/2, 64 dwords per col), 16B-group XOR swizzle.
__device__ __forceinline__ int uswz(int col, int krp) {
    return col * 64 + ((((krp >> 2) ^ (col & 15)) << 2) | (krp & 3));
}

__global__ __launch_bounds__(256)
void corr_onepass(const float* __restrict__ E, float* __restrict__ ws,
                  float* __restrict__ out) {
    __shared__ uint32 U[WDIM * 64];            // 64 KB
    __shared__ float red[4];
    __shared__ int amFinal;
    const int t = blockIdx.x, c = blockIdx.y;
    const int tid = threadIdx.x;
    const int bid = c * NT + t;

    // ---- zero my disjoint slice of the poisoned atomic region ----
    // atomicExch (device scope) lands at the coherent point, so later
    // cross-XCD atomicAdds see the zeros (plain stores would sit dirty in
    // this XCD's L2 and race with remote atomics).
    #pragma unroll
    for (int k = 0; k < 2; ++k) {
        const int r = k * 256 + tid;
        const int e = bid * ZSLICE + r;
        if (r < ZSLICE && e < WS_NATOM) atomicExch(&ws[e], 0.0f);
    }
    __syncthreads();                           // drains vmcnt: zeros complete
    unsigned ztarget = 0;
    if (tid == 0) {
        const unsigned zo = __hip_atomic_fetch_add(
            &g_zeroed, 1u, __ATOMIC_RELAXED, __HIP_MEMORY_SCOPE_AGENT);
        ztarget = zo - (zo % GRID_BLKS) + GRID_BLKS;
    }

    // ---------------- phase A: load E slab + cast to LDS ----------------
    const int ncg = (t == 1) ? 4 : 2;          // 64-col groups held in U
    const int gcol0 = (t == 2) ? 128 : 0;      // global col of U local col 0
    const int row0 = c * 128;
    const int c4 = tid & 15, rp = tid >> 4;

    for (int cg = 0; cg < ncg; ++cg) {
        const float* Eb = E + (size_t)row0 * WDIM + gcol0 + cg * 64;
        float4 fa[4], fb[4];
        #pragma unroll
        for (int p = 0; p < 4; ++p) {          // rowpairs rp+16p -> rows 2*,2*+1
            const int r0 = 2 * (rp + 16 * p);
            fa[p] = *(const float4*)(Eb + (size_t)r0 * WDIM + c4 * 4);
            fb[p] = *(const float4*)(Eb + (size_t)(r0 + 1) * WDIM + c4 * 4);
        }
        #pragma unroll
        for (int p = 0; p < 4; ++p) {
            const int krp = rp + 16 * p;
            const int colb = cg * 64 + c4 * 4;
            const float av[4] = {fa[p].x, fa[p].y, fa[p].z, fa[p].w};
            const float bv[4] = {fb[p].x, fb[p].y, fb[p].z, fb[p].w};
            #pragma unroll
            for (int i = 0; i < 4; ++i)
                U[uswz(colb + i, krp)] = pack2bf(av[i], bv[i]);
        }
    }
    __syncthreads();

    // colsum (t==1 blocks see all 256 cols). Keep in reg; publish after the
    // zeros-ready check. bf16-rounded inputs, f32 accumulate (err ~4e-5).
    float csum = 0.f;
    if (t == 1) {
        const int col = tid;
        #pragma unroll
        for (int g = 0; g < 16; ++g) {
            const uint4 v = *(const uint4*)&U[col * 64 + ((g ^ (col & 15)) << 2)];
            csum += bflo(v.x) + bfhi(v.x) + bflo(v.y) + bfhi(v.y)
                  + bflo(v.z) + bfhi(v.z) + bflo(v.w) + bfhi(v.w);
        }
    }

    // MFMA: wave w -> tile rows [32w,32w+32); local col = global - gcol0.
    const int w = tid >> 6, l = tid & 63, lm = l & 31;
    const int bBase = (t == 1) ? 128 : 0;
    const int colA = w * 32 + lm;

    f32x16 acc[4];
    #pragma unroll
    for (int n = 0; n < 4; ++n)
        #pragma unroll
        for (int r = 0; r < 16; ++r) acc[n][r] = 0.f;

    #pragma unroll
    for (int s8 = 0; s8 < 8; ++s8) {           // K = 128 = 8 steps of 16
        const int grp = 2 * s8 + (l >> 5);     // logical 16B group = k/8
        const bf16x8 a = *(const bf16x8*)&U[colA * 64 + ((grp ^ (colA & 15)) << 2)];
        #pragma unroll
        for (int n = 0; n < 4; ++n) {
            const int colB = bBase + n * 32 + lm;
            const bf16x8 b = *(const bf16x8*)&U[colB * 64 + ((grp ^ (colB & 15)) << 2)];
            acc[n] = __builtin_amdgcn_mfma_f32_32x32x16_bf16(a, b, acc[n], 0, 0, 0);
        }
    }

    // ---- wait until ALL blocks' zeros landed (they did so at launch;
    // we are ~µs past that -> expected zero spin) ----
    if (tid == 0) {
        while (__hip_atomic_load(&g_zeroed, __ATOMIC_RELAXED,
                                 __HIP_MEMORY_SCOPE_AGENT) < ztarget)
            __builtin_amdgcn_s_sleep(2);
    }
    __syncthreads();

    // ---- publish: f32 atomicAdd partial gram + colsum (coherent point) ----
    // C/D layout (m74/m101): col = lane&31, row = (r&3)+8*(r>>2)+4*(lane>>5)
    float* Gt = ws + WS_G + t * TILE_ELEMS;
    const int rbase = 32 * w + 4 * (l >> 5);
    #pragma unroll
    for (int n = 0; n < 4; ++n)
        #pragma unroll
        for (int r = 0; r < 16; ++r) {
            const int row = rbase + (r & 3) + 8 * (r >> 2);
            atomicAdd(&Gt[row * 128 + n * 32 + lm], acc[n][r]);
        }
    if (t == 1) atomicAdd(&ws[WS_CS + tid], csum);

    __syncthreads();                           // drains vmcnt: all adds complete
    if (tid == 0) {
        const unsigned d = __hip_atomic_fetch_add(
            &g_done, 1u, __ATOMIC_RELAXED, __HIP_MEMORY_SCOPE_AGENT);
        amFinal = ((d % GRID_BLKS) == GRID_BLKS - 1);
    }
    __syncthreads();
    if (!amFinal) return;                      // 191 blocks exit; no spinning

    // ---------------- final block: loss + sqrt ----------------
    // Atomic reads (atomicAdd(p,0)) execute at the coherent point -> see all
    // completed adds; same pattern as the verified round-0 lossacc read.
    float* muS = (float*)U;                    // U is dead; reuse LDS
    if (tid < WDIM)
        muS[tid] = atomicAdd(&ws[WS_CS + tid], 0.0f) * (1.0f / (float)BROWS);
    __syncthreads();

    float v = 0.f;
    #pragma unroll 8
    for (int e = tid; e < NT * TILE_ELEMS; e += 256) {
        const int tt = e >> 14, local = e & 16383;
        const int i = ((tt == 2) ? 128 : 0) + (local >> 7);
        const int j = ((tt == 0) ? 0 : 128) + (local & 127);
        const float g = atomicAdd(&ws[WS_G + e], 0.0f);
        const float diff = g * (1.0f / (float)BROWS) - muS[i] * muS[j]
                         - ((i == j) ? 1.0f : 0.0f);
        v += ((tt == 1) ? 2.0f : 1.0f) * diff * diff;
    }

    #pragma unroll
    for (int o = 32; o > 0; o >>= 1) v += __shfl_down(v, o, 64);
    if ((tid & 63) == 0) red[tid >> 6] = v;
    __syncthreads();
    if (tid == 0)
        out[0] = sqrtf(red[0] + red[1] + red[2] + red[3]);
}

// ---------------------------------------------------------------------- host
extern "C" void kernel_launch(void* const* d_in, const int* in_sizes, int n_in,
                              void* d_out, int out_size, void* d_ws, size_t ws_size,
                              hipStream_t stream) {
    const float* E = (const float*)d_in[0];
    // d_in[1] (label) unused by the reference math.
    float* out = (float*)d_out;
    float* ws = (float*)d_ws;

    corr_onepass<<<dim3(NT, CHUNKS), 256, 0, stream>>>(E, ws, out);
}